// Round 1
// baseline (396.994 us; speedup 1.0000x reference)
//
#include <hip/hip_runtime.h>
#include <hip/hip_bf16.h>

typedef __bf16 bf16_t;
typedef short  s4    __attribute__((ext_vector_type(4)));
typedef float  f32x4 __attribute__((ext_vector_type(4)));

#define TPW   16                     // 16-sample tiles per wave
#define WAVES 4
#define ROWS_PER_BLOCK (WAVES * TPW * 16)   // 1024 -> grid = 1024 = 4 blocks/CU, one round

__device__ __forceinline__ short bfs(float f) {
    return __builtin_bit_cast(short, (bf16_t)f);
}
__device__ __forceinline__ s4 pack4(f32x4 a) {
    s4 r; r[0]=bfs(a[0]); r[1]=bfs(a[1]); r[2]=bfs(a[2]); r[3]=bfs(a[3]); return r;
}
__device__ __forceinline__ s4 relu_pack4(f32x4 a) {
    s4 r;
    r[0]=bfs(fmaxf(a[0],0.f)); r[1]=bfs(fmaxf(a[1],0.f));
    r[2]=bfs(fmaxf(a[2],0.f)); r[3]=bfs(fmaxf(a[3],0.f));
    return r;
}
// D = A*B + C, 16x16x16 bf16. Layout identity used throughout:
// A[m=n][k=4q+i] (reg i) ; B[k=4q+i][c=n] (reg i) ; D[row=4q+r][c=n] (reg r)
// => a layer's D regs are exactly the next layer's B regs (same lane, same reg).
#define MFMA16(a,b,c) __builtin_amdgcn_mfma_f32_16x16x16bf16_1k(a, b, c, 0, 0, 0)

__global__ __launch_bounds__(256, 4) void nerf_fused(
    const float* __restrict__ pos, const float* __restrict__ dir,
    const float* __restrict__ W1, const float* __restrict__ b1,
    const float* __restrict__ W2, const float* __restrict__ b2,
    const float* __restrict__ W3, const float* __restrict__ b3,
    const float* __restrict__ W4, const float* __restrict__ b4,
    const float* __restrict__ W5, const float* __restrict__ b5,
    float* __restrict__ outD, float* __restrict__ outC)
{
    const int tid  = threadIdx.x;
    const int w    = tid >> 6;
    const int lane = tid & 63;
    const int q    = lane >> 4;    // quad 0..3
    const int n    = lane & 15;    // A row / B col / sample-within-tile

    // ---------- weight A-fragments: wa[tile][ktile][i] = W^T[16t+n][16kt+4q+i] ----------
    s4 wa1[4][2], wa2[4], wa3[4][2], wa4[4][4], wa5[4];
    #pragma unroll
    for (int t = 0; t < 4; ++t)
        #pragma unroll
        for (int kt = 0; kt < 2; ++kt)
            #pragma unroll
            for (int i = 0; i < 4; ++i)
                wa1[t][kt][i] = bfs(W1[(16*kt + 4*q + i) * 64 + 16*t + n]);   // [32,64]
    #pragma unroll
    for (int kt = 0; kt < 4; ++kt)
        #pragma unroll
        for (int i = 0; i < 4; ++i)
            wa2[kt][i] = bfs(W2[(16*kt + 4*q + i) * 16 + n]);                 // [64,16]
    #pragma unroll
    for (int t = 0; t < 4; ++t)
        #pragma unroll
        for (int kt = 0; kt < 2; ++kt)
            #pragma unroll
            for (int i = 0; i < 4; ++i)
                wa3[t][kt][i] = bfs(W3[(16*kt + 4*q + i) * 64 + 16*t + n]);   // [32,64]
    #pragma unroll
    for (int t = 0; t < 4; ++t)
        #pragma unroll
        for (int kt = 0; kt < 4; ++kt)
            #pragma unroll
            for (int i = 0; i < 4; ++i)
                wa4[t][kt][i] = bfs(W4[(16*kt + 4*q + i) * 64 + 16*t + n]);   // [64,64]
    #pragma unroll
    for (int kt = 0; kt < 4; ++kt)
        #pragma unroll
        for (int i = 0; i < 4; ++i)
            wa5[kt][i] = (n < 3) ? bfs(W5[(16*kt + 4*q + i) * 3 + n]) : (short)0; // [64,3] pad

    // ---------- bias C-initializers (channel index = 4q+r within tile t) ----------
    f32x4 bi1[4], bi3[4], bi4[4], bi2, bi5;
    #pragma unroll
    for (int t = 0; t < 4; ++t)
        #pragma unroll
        for (int r = 0; r < 4; ++r) {
            bi1[t][r] = b1[16*t + 4*q + r];
            bi3[t][r] = b3[16*t + 4*q + r];
            bi4[t][r] = b4[16*t + 4*q + r];
        }
    #pragma unroll
    for (int r = 0; r < 4; ++r) {
        bi2[r] = b2[4*q + r];
        bi5[r] = (q == 0 && r < 3) ? b5[r] : 0.f;
    }

    const int waveRow0 = blockIdx.x * ROWS_PER_BLOCK + w * (TPW * 16);

    // per-lane streaming pointers (constant per-tile strides; no per-tile 64-bit mults)
    const float* pp = pos  + (size_t)(waveRow0 + n) * 32 + 4*q;
    const float* dp = dir  + (size_t)(waveRow0 + n) * 3;
    float*       pD = outD + (size_t)(waveRow0 + n) * 16 + 4*q;
    float*       pC = outC + (size_t)(waveRow0 + n) * 3;   // only used by q==0 lanes

    // prefetched raw inputs for tile 0
    f32x4 pa = *(const f32x4*)pp;
    f32x4 pb = *(const f32x4*)(pp + 16);
    float dx = dp[0];
    float dy = dp[1];
    float dz = dp[2];

    for (int t = 0; t < TPW; ++t) {
        const float* ppn = pp + ((t + 1 < TPW) ? 16 * 32 : 0);
        const float* dpn = dp + ((t + 1 < TPW) ? 16 * 3  : 0);
        f32x4 pa2 = *(const f32x4*)ppn;
        f32x4 pb2 = *(const f32x4*)(ppn + 16);
        float dx2 = dpn[0];
        float dy2 = dpn[1];
        float dz2 = dpn[2];

        // B-frags of X^T: B[k=16kt+4q+i][s=n] = pos[row+n][16kt+4q+i]
        s4 xb0 = pack4(pa), xb1 = pack4(pb);

        // ---- L1: H^T = W1^T · X^T  (4 h-tiles, K=32) ----
        s4 hf[4];
        #pragma unroll
        for (int tt = 0; tt < 4; ++tt) {
            f32x4 h = MFMA16(wa1[tt][0], xb0, bi1[tt]);
            h = MFMA16(wa1[tt][1], xb1, h);
            hf[tt] = relu_pack4(h);          // D regs == next-layer B regs
        }

        // ---- L2: density^T = W2^T · H^T  (K=64, no relu) ----
        f32x4 d2 = bi2;
        #pragma unroll
        for (int kt = 0; kt < 4; ++kt)
            d2 = MFMA16(wa2[kt], hf[kt], d2);   // lane(q,n) reg r = density[s=n][c=4q+r]

        // direct coalesced density store: lane(q,n) holds channels 4q..4q+3 of
        // sample n -> contiguous 16B; the wave covers one contiguous 1 KiB segment.
        *(f32x4*)pD = d2;

        // ---- L3 B-operand: kt=0 raw density (same regs), kt=1 SH in-register ----
        s4 cf0 = pack4(d2);
        f32x4 shv;
        {
            const float xx = dx*dx, yy = dy*dy, zz = dz*dz;
            if (q == 0) {
                shv[0] = 0.28209479177387814f;
                shv[1] = 0.4886025119029199f * dy;
                shv[2] = 0.4886025119029199f * dz;
                shv[3] = 0.4886025119029199f * dx;
            } else if (q == 1) {
                shv[0] = 1.0925484305920792f * dx * dy;
                shv[1] = 1.0925484305920792f * dy * dz;
                shv[2] = 0.9461746957575601f * zz - 0.31539156525252f;
                shv[3] = 1.0925484305920792f * dx * dz;
            } else if (q == 2) {
                shv[0] = 0.5462742152960396f * (xx - yy);
                shv[1] = 0.5900435899266435f * dy * (3.f*xx - yy);
                shv[2] = 2.890611442640554f * dx * dy * dz;
                shv[3] = 0.4570457994644658f * dy * (5.f*zz - 1.f);
            } else {
                shv[0] = 0.3731763325901154f * dz * (5.f*zz - 3.f);
                shv[1] = 0.4570457994644658f * dx * (5.f*zz - 1.f);
                shv[2] = 1.445305721320277f  * dz * (xx - yy);
                shv[3] = 0.5900435899266435f * dx * (xx - 3.f*yy);
            }
        }
        s4 cf1 = pack4(shv);

        // ---- L3: relu(W3^T · concat^T)  (4 h-tiles, K=32) ----
        s4 gf[4];
        #pragma unroll
        for (int tt = 0; tt < 4; ++tt) {
            f32x4 g = MFMA16(wa3[tt][0], cf0, bi3[tt]);
            g = MFMA16(wa3[tt][1], cf1, g);
            gf[tt] = relu_pack4(g);
        }

        // ---- L4: relu(W4^T · H3^T)  (4 h-tiles, K=64) ----
        s4 ef[4];
        #pragma unroll
        for (int tt = 0; tt < 4; ++tt) {
            f32x4 e = bi4[tt];
            #pragma unroll
            for (int kt = 0; kt < 4; ++kt)
                e = MFMA16(wa4[tt][kt], gf[kt], e);
            ef[tt] = relu_pack4(e);
        }

        // ---- L5: color^T = W5^T · H4^T  (K=64) + sigmoid ----
        f32x4 c5 = bi5;
        #pragma unroll
        for (int kt = 0; kt < 4; ++kt)
            c5 = MFMA16(wa5[kt], ef[kt], c5);   // valid only q==0, r<3: color[s=n][c=r]

        // branchless sigmoid on all lanes; only q==0 lanes hold valid data + store
        f32x4 cv;
        cv[0] = 1.f / (1.f + __expf(-c5[0]));
        cv[1] = 1.f / (1.f + __expf(-c5[1]));
        cv[2] = 1.f / (1.f + __expf(-c5[2]));
        if (q == 0) {
            pC[0] = cv[0];
            pC[1] = cv[1];
            pC[2] = cv[2];
        }

        pp += 16 * 32; dp += 16 * 3; pD += 16 * 16; pC += 16 * 3;
        pa = pa2; pb = pb2; dx = dx2; dy = dy2; dz = dz2;
    }
}

extern "C" void kernel_launch(void* const* d_in, const int* in_sizes, int n_in,
                              void* d_out, int out_size, void* d_ws, size_t ws_size,
                              hipStream_t stream) {
    const float* pos = (const float*)d_in[0];
    const float* dir = (const float*)d_in[1];
    const float* W1  = (const float*)d_in[2];
    const float* b1  = (const float*)d_in[3];
    const float* W2  = (const float*)d_in[4];
    const float* b2  = (const float*)d_in[5];
    const float* W3  = (const float*)d_in[6];
    const float* b3  = (const float*)d_in[7];
    const float* W4  = (const float*)d_in[8];
    const float* b4  = (const float*)d_in[9];
    const float* W5  = (const float*)d_in[10];
    const float* b5  = (const float*)d_in[11];

    const int N = in_sizes[0] / 32;           // 1<<20
    float* outD = (float*)d_out;              // [N,16]
    float* outC = outD + (size_t)N * 16;      // [N,3]

    const int grid = N / ROWS_PER_BLOCK;      // 1024
    nerf_fused<<<grid, WAVES * 64, 0, stream>>>(pos, dir, W1, b1, W2, b2, W3, b3,
                                                W4, b4, W5, b5, outD, outC);
}

// Round 2
// 256.837 us; speedup vs baseline: 1.5457x; 1.5457x over previous
//
#include <hip/hip_runtime.h>
#include <hip/hip_bf16.h>

typedef __bf16 bf16_t;
typedef short  s4    __attribute__((ext_vector_type(4)));
typedef float  f32x4 __attribute__((ext_vector_type(4)));

#define TPW   16                     // 16-sample tiles per wave
#define WAVES 4
#define ROWS_PER_BLOCK (WAVES * TPW * 16)   // 1024 -> grid = 1024 = 4 blocks/CU, one round

__device__ __forceinline__ short bfs(float f) {
    return __builtin_bit_cast(short, (bf16_t)f);
}
__device__ __forceinline__ s4 pack4(f32x4 a) {
    s4 r; r[0]=bfs(a[0]); r[1]=bfs(a[1]); r[2]=bfs(a[2]); r[3]=bfs(a[3]); return r;
}
__device__ __forceinline__ s4 relu_pack4(f32x4 a) {
    s4 r;
    r[0]=bfs(fmaxf(a[0],0.f)); r[1]=bfs(fmaxf(a[1],0.f));
    r[2]=bfs(fmaxf(a[2],0.f)); r[3]=bfs(fmaxf(a[3],0.f));
    return r;
}
// D = A*B + C, 16x16x16 bf16. Layout identity used throughout:
// A[m=n][k=4q+i] (reg i) ; B[k=4q+i][c=n] (reg i) ; D[row=4q+r][c=n] (reg r)
// => a layer's D regs are exactly the next layer's B regs (same lane, same reg).
#define MFMA16(a,b,c) __builtin_amdgcn_mfma_f32_16x16x16bf16_1k(a, b, c, 0, 0, 0)

// NOTE: plain __launch_bounds__(256). Adding a min-waves/EU of 4 (VGPR cap 128)
// forces the ~136-value working set (80 VGPR weights + 56 VGPR biases) to the
// 64-VGPR tier -> ~70 regs spilled -> FETCH 530MB / WRITE 206MB of scratch
// traffic and a 2x regression (measured round 1). 120 VGPRs holds it spill-free.
__global__ __launch_bounds__(256) void nerf_fused(
    const float* __restrict__ pos, const float* __restrict__ dir,
    const float* __restrict__ W1, const float* __restrict__ b1,
    const float* __restrict__ W2, const float* __restrict__ b2,
    const float* __restrict__ W3, const float* __restrict__ b3,
    const float* __restrict__ W4, const float* __restrict__ b4,
    const float* __restrict__ W5, const float* __restrict__ b5,
    float* __restrict__ outD, float* __restrict__ outC)
{
    const int tid  = threadIdx.x;
    const int w    = tid >> 6;
    const int lane = tid & 63;
    const int q    = lane >> 4;    // quad 0..3
    const int n    = lane & 15;    // A row / B col / sample-within-tile

    // ---------- weight A-fragments: wa[tile][ktile][i] = W^T[16t+n][16kt+4q+i] ----------
    s4 wa1[4][2], wa2[4], wa3[4][2], wa4[4][4], wa5[4];
    #pragma unroll
    for (int t = 0; t < 4; ++t)
        #pragma unroll
        for (int kt = 0; kt < 2; ++kt)
            #pragma unroll
            for (int i = 0; i < 4; ++i)
                wa1[t][kt][i] = bfs(W1[(16*kt + 4*q + i) * 64 + 16*t + n]);   // [32,64]
    #pragma unroll
    for (int kt = 0; kt < 4; ++kt)
        #pragma unroll
        for (int i = 0; i < 4; ++i)
            wa2[kt][i] = bfs(W2[(16*kt + 4*q + i) * 16 + n]);                 // [64,16]
    #pragma unroll
    for (int t = 0; t < 4; ++t)
        #pragma unroll
        for (int kt = 0; kt < 2; ++kt)
            #pragma unroll
            for (int i = 0; i < 4; ++i)
                wa3[t][kt][i] = bfs(W3[(16*kt + 4*q + i) * 64 + 16*t + n]);   // [32,64]
    #pragma unroll
    for (int t = 0; t < 4; ++t)
        #pragma unroll
        for (int kt = 0; kt < 4; ++kt)
            #pragma unroll
            for (int i = 0; i < 4; ++i)
                wa4[t][kt][i] = bfs(W4[(16*kt + 4*q + i) * 64 + 16*t + n]);   // [64,64]
    #pragma unroll
    for (int kt = 0; kt < 4; ++kt)
        #pragma unroll
        for (int i = 0; i < 4; ++i)
            wa5[kt][i] = (n < 3) ? bfs(W5[(16*kt + 4*q + i) * 3 + n]) : (short)0; // [64,3] pad

    // ---------- bias C-initializers (channel index = 4q+r within tile t) ----------
    f32x4 bi1[4], bi3[4], bi4[4], bi2, bi5;
    #pragma unroll
    for (int t = 0; t < 4; ++t)
        #pragma unroll
        for (int r = 0; r < 4; ++r) {
            bi1[t][r] = b1[16*t + 4*q + r];
            bi3[t][r] = b3[16*t + 4*q + r];
            bi4[t][r] = b4[16*t + 4*q + r];
        }
    #pragma unroll
    for (int r = 0; r < 4; ++r) {
        bi2[r] = b2[4*q + r];
        bi5[r] = (q == 0 && r < 3) ? b5[r] : 0.f;
    }

    const int waveRow0 = blockIdx.x * ROWS_PER_BLOCK + w * (TPW * 16);

    // per-lane streaming pointers (constant per-tile strides; no per-tile 64-bit mults)
    const float* pp = pos  + (size_t)(waveRow0 + n) * 32 + 4*q;
    const float* dp = dir  + (size_t)(waveRow0 + n) * 3;
    float*       pD = outD + (size_t)(waveRow0 + n) * 16 + 4*q;
    float*       pC = outC + (size_t)(waveRow0 + n) * 3;   // only used by q==0 lanes

    // prefetched raw inputs for tile 0
    f32x4 pa = *(const f32x4*)pp;
    f32x4 pb = *(const f32x4*)(pp + 16);
    float dx = dp[0];
    float dy = dp[1];
    float dz = dp[2];

    for (int t = 0; t < TPW; ++t) {
        const float* ppn = pp + ((t + 1 < TPW) ? 16 * 32 : 0);
        const float* dpn = dp + ((t + 1 < TPW) ? 16 * 3  : 0);
        f32x4 pa2 = *(const f32x4*)ppn;
        f32x4 pb2 = *(const f32x4*)(ppn + 16);
        float dx2 = dpn[0];
        float dy2 = dpn[1];
        float dz2 = dpn[2];

        // B-frags of X^T: B[k=16kt+4q+i][s=n] = pos[row+n][16kt+4q+i]
        s4 xb0 = pack4(pa), xb1 = pack4(pb);

        // ---- L1: H^T = W1^T · X^T  (4 h-tiles, K=32) ----
        s4 hf[4];
        #pragma unroll
        for (int tt = 0; tt < 4; ++tt) {
            f32x4 h = MFMA16(wa1[tt][0], xb0, bi1[tt]);
            h = MFMA16(wa1[tt][1], xb1, h);
            hf[tt] = relu_pack4(h);          // D regs == next-layer B regs
        }

        // ---- L2: density^T = W2^T · H^T  (K=64, no relu) ----
        f32x4 d2 = bi2;
        #pragma unroll
        for (int kt = 0; kt < 4; ++kt)
            d2 = MFMA16(wa2[kt], hf[kt], d2);   // lane(q,n) reg r = density[s=n][c=4q+r]

        // direct coalesced density store: lane(q,n) holds channels 4q..4q+3 of
        // sample n -> contiguous 16B; the wave covers one contiguous 1 KiB segment.
        *(f32x4*)pD = d2;

        // ---- L3 B-operand: kt=0 raw density (same regs), kt=1 SH in-register ----
        s4 cf0 = pack4(d2);
        f32x4 shv;
        {
            const float xx = dx*dx, yy = dy*dy, zz = dz*dz;
            if (q == 0) {
                shv[0] = 0.28209479177387814f;
                shv[1] = 0.4886025119029199f * dy;
                shv[2] = 0.4886025119029199f * dz;
                shv[3] = 0.4886025119029199f * dx;
            } else if (q == 1) {
                shv[0] = 1.0925484305920792f * dx * dy;
                shv[1] = 1.0925484305920792f * dy * dz;
                shv[2] = 0.9461746957575601f * zz - 0.31539156525252f;
                shv[3] = 1.0925484305920792f * dx * dz;
            } else if (q == 2) {
                shv[0] = 0.5462742152960396f * (xx - yy);
                shv[1] = 0.5900435899266435f * dy * (3.f*xx - yy);
                shv[2] = 2.890611442640554f * dx * dy * dz;
                shv[3] = 0.4570457994644658f * dy * (5.f*zz - 1.f);
            } else {
                shv[0] = 0.3731763325901154f * dz * (5.f*zz - 3.f);
                shv[1] = 0.4570457994644658f * dx * (5.f*zz - 1.f);
                shv[2] = 1.445305721320277f  * dz * (xx - yy);
                shv[3] = 0.5900435899266435f * dx * (xx - 3.f*yy);
            }
        }
        s4 cf1 = pack4(shv);

        // ---- L3: relu(W3^T · concat^T)  (4 h-tiles, K=32) ----
        s4 gf[4];
        #pragma unroll
        for (int tt = 0; tt < 4; ++tt) {
            f32x4 g = MFMA16(wa3[tt][0], cf0, bi3[tt]);
            g = MFMA16(wa3[tt][1], cf1, g);
            gf[tt] = relu_pack4(g);
        }

        // ---- L4: relu(W4^T · H3^T)  (4 h-tiles, K=64) ----
        s4 ef[4];
        #pragma unroll
        for (int tt = 0; tt < 4; ++tt) {
            f32x4 e = bi4[tt];
            #pragma unroll
            for (int kt = 0; kt < 4; ++kt)
                e = MFMA16(wa4[tt][kt], gf[kt], e);
            ef[tt] = relu_pack4(e);
        }

        // ---- L5: color^T = W5^T · H4^T  (K=64) + sigmoid ----
        f32x4 c5 = bi5;
        #pragma unroll
        for (int kt = 0; kt < 4; ++kt)
            c5 = MFMA16(wa5[kt], ef[kt], c5);   // valid only q==0, r<3: color[s=n][c=r]

        // branchless sigmoid on all lanes; only q==0 lanes hold valid data + store
        f32x4 cv;
        cv[0] = 1.f / (1.f + __expf(-c5[0]));
        cv[1] = 1.f / (1.f + __expf(-c5[1]));
        cv[2] = 1.f / (1.f + __expf(-c5[2]));
        if (q == 0) {
            pC[0] = cv[0];
            pC[1] = cv[1];
            pC[2] = cv[2];
        }

        pp += 16 * 32; dp += 16 * 3; pD += 16 * 16; pC += 16 * 3;
        pa = pa2; pb = pb2; dx = dx2; dy = dy2; dz = dz2;
    }
}

extern "C" void kernel_launch(void* const* d_in, const int* in_sizes, int n_in,
                              void* d_out, int out_size, void* d_ws, size_t ws_size,
                              hipStream_t stream) {
    const float* pos = (const float*)d_in[0];
    const float* dir = (const float*)d_in[1];
    const float* W1  = (const float*)d_in[2];
    const float* b1  = (const float*)d_in[3];
    const float* W2  = (const float*)d_in[4];
    const float* b2  = (const float*)d_in[5];
    const float* W3  = (const float*)d_in[6];
    const float* b3  = (const float*)d_in[7];
    const float* W4  = (const float*)d_in[8];
    const float* b4  = (const float*)d_in[9];
    const float* W5  = (const float*)d_in[10];
    const float* b5  = (const float*)d_in[11];

    const int N = in_sizes[0] / 32;           // 1<<20
    float* outD = (float*)d_out;              // [N,16]
    float* outC = outD + (size_t)N * 16;      // [N,3]

    const int grid = N / ROWS_PER_BLOCK;      // 1024
    nerf_fused<<<grid, WAVES * 64, 0, stream>>>(pos, dir, W1, b1, W2, b2, W3, b3,
                                                W4, b4, W5, b5, outD, outC);
}

// Round 3
// 253.665 us; speedup vs baseline: 1.5650x; 1.0125x over previous
//
#include <hip/hip_runtime.h>
#include <hip/hip_bf16.h>

typedef __bf16 bf16_t;
typedef short  s4    __attribute__((ext_vector_type(4)));
typedef short  s8    __attribute__((ext_vector_type(8)));
typedef float  f32x4 __attribute__((ext_vector_type(4)));

#define TPW   16                     // 16-sample tiles per wave
#define WAVES 4
#define ROWS_PER_BLOCK (WAVES * TPW * 16)   // 1024 -> grid = 1024 = 4 blocks/CU

__device__ __forceinline__ short bfs(float f) {
    return __builtin_bit_cast(short, (bf16_t)f);
}
__device__ __forceinline__ s4 pack4(f32x4 a) {
    s4 r; r[0]=bfs(a[0]); r[1]=bfs(a[1]); r[2]=bfs(a[2]); r[3]=bfs(a[3]); return r;
}
__device__ __forceinline__ s4 relu_pack4(f32x4 a) {
    s4 r;
    r[0]=bfs(fmaxf(a[0],0.f)); r[1]=bfs(fmaxf(a[1],0.f));
    r[2]=bfs(fmaxf(a[2],0.f)); r[3]=bfs(fmaxf(a[3],0.f));
    return r;
}
__device__ __forceinline__ s8 cat(s4 a, s4 b) {
    return __builtin_shufflevector(a, b, 0, 1, 2, 3, 4, 5, 6, 7);
}
// Native gfx950 shape: D = A*B + C, 16x16x32 bf16 (16384 FLOP/instr, ~5cyc).
// Layout identity (k-map agnostic): MFMA pairs A(lane-group g, elem i) with
// B(g, i) for one shared k, and A/B layouts are symmetric. We define OUR k
// order as concat of the two legacy x16 fragments (elem i<4 -> k=4q+i of kt_lo,
// i>=4 -> k=4q+(i-4) of kt_hi) for BOTH the weight gather (A) and the data (B),
// so the contraction is correct regardless of the HW's internal k ordering.
// C/D layout is identical to x16 (m89-verified): col=lane&15, row=4*(lane>>4)+reg
// => a layer's D regs are exactly the next layer's B regs (after relu+pack+cat).
#define MFMA32(a,b,c) __builtin_amdgcn_mfma_f32_16x16x32_bf16(a, b, c, 0, 0, 0)

// NOTE: plain __launch_bounds__(256). A min-waves/EU of 4 (VGPR cap 128) forces
// the ~136-value working set (80 VGPR weights + 56 VGPR biases) into spills:
// FETCH 530MB / WRITE 206MB scratch traffic, 2x regression (measured round 1).
__global__ __launch_bounds__(256) void nerf_fused(
    const float* __restrict__ pos, const float* __restrict__ dir,
    const float* __restrict__ W1, const float* __restrict__ b1,
    const float* __restrict__ W2, const float* __restrict__ b2,
    const float* __restrict__ W3, const float* __restrict__ b3,
    const float* __restrict__ W4, const float* __restrict__ b4,
    const float* __restrict__ W5, const float* __restrict__ b5,
    float* __restrict__ outD, float* __restrict__ outC)
{
    const int tid  = threadIdx.x;
    const int w    = tid >> 6;
    const int lane = tid & 63;
    const int q    = lane >> 4;    // lane-group 0..3
    const int n    = lane & 15;    // A row / B col / sample-within-tile

    // ---------- weight A-fragments (s8 = concat of two 16-k subtiles) ----------
    // elem 4*h+i (h=0,1): W[(16*(kt_base+h) + 4q + i)][out-channel]
    s8 wa1[4], wa2x[2], wa3[4], wa4x[4][2], wa5x[2];
    #pragma unroll
    for (int t = 0; t < 4; ++t)
        #pragma unroll
        for (int h = 0; h < 2; ++h)
            #pragma unroll
            for (int i = 0; i < 4; ++i)
                wa1[t][4*h+i] = bfs(W1[(16*h + 4*q + i) * 64 + 16*t + n]);      // [32,64]
    #pragma unroll
    for (int j = 0; j < 2; ++j)
        #pragma unroll
        for (int h = 0; h < 2; ++h)
            #pragma unroll
            for (int i = 0; i < 4; ++i)
                wa2x[j][4*h+i] = bfs(W2[(16*(2*j+h) + 4*q + i) * 16 + n]);      // [64,16]
    #pragma unroll
    for (int t = 0; t < 4; ++t)
        #pragma unroll
        for (int h = 0; h < 2; ++h)
            #pragma unroll
            for (int i = 0; i < 4; ++i)
                wa3[t][4*h+i] = bfs(W3[(16*h + 4*q + i) * 64 + 16*t + n]);      // [32,64]
    #pragma unroll
    for (int t = 0; t < 4; ++t)
        #pragma unroll
        for (int j = 0; j < 2; ++j)
            #pragma unroll
            for (int h = 0; h < 2; ++h)
                #pragma unroll
                for (int i = 0; i < 4; ++i)
                    wa4x[t][j][4*h+i] = bfs(W4[(16*(2*j+h) + 4*q + i) * 64 + 16*t + n]); // [64,64]
    #pragma unroll
    for (int j = 0; j < 2; ++j)
        #pragma unroll
        for (int h = 0; h < 2; ++h)
            #pragma unroll
            for (int i = 0; i < 4; ++i)
                wa5x[j][4*h+i] = (n < 3) ? bfs(W5[(16*(2*j+h) + 4*q + i) * 3 + n])
                                         : (short)0;                             // [64,3] pad

    // ---------- bias C-initializers (channel index = 4q+r within tile t) ----------
    f32x4 bi1[4], bi3[4], bi4[4], bi2, bi5;
    #pragma unroll
    for (int t = 0; t < 4; ++t)
        #pragma unroll
        for (int r = 0; r < 4; ++r) {
            bi1[t][r] = b1[16*t + 4*q + r];
            bi3[t][r] = b3[16*t + 4*q + r];
            bi4[t][r] = b4[16*t + 4*q + r];
        }
    #pragma unroll
    for (int r = 0; r < 4; ++r) {
        bi2[r] = b2[4*q + r];
        bi5[r] = (q == 0 && r < 3) ? b5[r] : 0.f;
    }

    const int waveRow0 = blockIdx.x * ROWS_PER_BLOCK + w * (TPW * 16);

    // per-lane streaming pointers (constant per-tile strides)
    const float* pp = pos  + (size_t)(waveRow0 + n) * 32 + 4*q;
    const float* dp = dir  + (size_t)(waveRow0 + n) * 3;
    float*       pD = outD + (size_t)(waveRow0 + n) * 16 + 4*q;
    float*       pC = outC + (size_t)(waveRow0 + n) * 3;   // only used by q==0 lanes

    // prefetched raw inputs for tile 0
    f32x4 pa = *(const f32x4*)pp;
    f32x4 pb = *(const f32x4*)(pp + 16);
    float dx = dp[0];
    float dy = dp[1];
    float dz = dp[2];

    for (int t = 0; t < TPW; ++t) {
        const float* ppn = pp + ((t + 1 < TPW) ? 16 * 32 : 0);
        const float* dpn = dp + ((t + 1 < TPW) ? 16 * 3  : 0);
        f32x4 pa2 = *(const f32x4*)ppn;
        f32x4 pb2 = *(const f32x4*)(ppn + 16);
        float dx2 = dpn[0];
        float dy2 = dpn[1];
        float dz2 = dpn[2];

        // B-frag of X^T: elem 4h+i = pos[row+n][16h+4q+i]  (our k order)
        s8 xb = cat(pack4(pa), pack4(pb));

        // ---- L1: H^T = W1^T · X^T  (4 h-tiles, K=32, single MFMA each) ----
        s4 hf[4];
        #pragma unroll
        for (int tt = 0; tt < 4; ++tt) {
            f32x4 h = MFMA32(wa1[tt], xb, bi1[tt]);
            hf[tt] = relu_pack4(h);          // D regs == next-layer B regs
        }

        // ---- L2: density^T = W2^T · H^T  (K=64 -> 2 chained MFMAs, no relu) ----
        f32x4 d2 = MFMA32(wa2x[0], cat(hf[0], hf[1]), bi2);
        d2 = MFMA32(wa2x[1], cat(hf[2], hf[3]), d2);   // lane(q,n) reg r = density[s=n][c=4q+r]

        // direct coalesced density store: lane(q,n) holds channels 4q..4q+3 of
        // sample n -> contiguous 16B; the wave covers one contiguous 1 KiB segment.
        *(f32x4*)pD = d2;

        // ---- L3 B-operand: low half raw density (same regs), high half SH ----
        f32x4 shv;
        {
            const float xx = dx*dx, yy = dy*dy, zz = dz*dz;
            if (q == 0) {
                shv[0] = 0.28209479177387814f;
                shv[1] = 0.4886025119029199f * dy;
                shv[2] = 0.4886025119029199f * dz;
                shv[3] = 0.4886025119029199f * dx;
            } else if (q == 1) {
                shv[0] = 1.0925484305920792f * dx * dy;
                shv[1] = 1.0925484305920792f * dy * dz;
                shv[2] = 0.9461746957575601f * zz - 0.31539156525252f;
                shv[3] = 1.0925484305920792f * dx * dz;
            } else if (q == 2) {
                shv[0] = 0.5462742152960396f * (xx - yy);
                shv[1] = 0.5900435899266435f * dy * (3.f*xx - yy);
                shv[2] = 2.890611442640554f * dx * dy * dz;
                shv[3] = 0.4570457994644658f * dy * (5.f*zz - 1.f);
            } else {
                shv[0] = 0.3731763325901154f * dz * (5.f*zz - 3.f);
                shv[1] = 0.4570457994644658f * dx * (5.f*zz - 1.f);
                shv[2] = 1.445305721320277f  * dz * (xx - yy);
                shv[3] = 0.5900435899266435f * dx * (xx - 3.f*yy);
            }
        }
        s8 cf = cat(pack4(d2), pack4(shv));

        // ---- L3: relu(W3^T · concat^T)  (4 h-tiles, K=32, single MFMA each) ----
        s4 gf[4];
        #pragma unroll
        for (int tt = 0; tt < 4; ++tt) {
            f32x4 g = MFMA32(wa3[tt], cf, bi3[tt]);
            gf[tt] = relu_pack4(g);
        }

        // ---- L4: relu(W4^T · H3^T)  (4 h-tiles, K=64 -> 2 chained MFMAs) ----
        s8 gl = cat(gf[0], gf[1]), gh = cat(gf[2], gf[3]);
        s4 ef[4];
        #pragma unroll
        for (int tt = 0; tt < 4; ++tt) {
            f32x4 e = MFMA32(wa4x[tt][0], gl, bi4[tt]);
            e = MFMA32(wa4x[tt][1], gh, e);
            ef[tt] = relu_pack4(e);
        }

        // ---- L5: color^T = W5^T · H4^T  (K=64 -> 2 chained MFMAs) + sigmoid ----
        f32x4 c5 = MFMA32(wa5x[0], cat(ef[0], ef[1]), bi5);
        c5 = MFMA32(wa5x[1], cat(ef[2], ef[3]), c5);   // valid only q==0, r<3

        // branchless sigmoid on all lanes; only q==0 lanes hold valid data + store
        f32x4 cv;
        cv[0] = 1.f / (1.f + __expf(-c5[0]));
        cv[1] = 1.f / (1.f + __expf(-c5[1]));
        cv[2] = 1.f / (1.f + __expf(-c5[2]));
        if (q == 0) {
            pC[0] = cv[0];
            pC[1] = cv[1];
            pC[2] = cv[2];
        }

        pp += 16 * 32; dp += 16 * 3; pD += 16 * 16; pC += 16 * 3;
        pa = pa2; pb = pb2; dx = dx2; dy = dy2; dz = dz2;
    }
}

extern "C" void kernel_launch(void* const* d_in, const int* in_sizes, int n_in,
                              void* d_out, int out_size, void* d_ws, size_t ws_size,
                              hipStream_t stream) {
    const float* pos = (const float*)d_in[0];
    const float* dir = (const float*)d_in[1];
    const float* W1  = (const float*)d_in[2];
    const float* b1  = (const float*)d_in[3];
    const float* W2  = (const float*)d_in[4];
    const float* b2  = (const float*)d_in[5];
    const float* W3  = (const float*)d_in[6];
    const float* b3  = (const float*)d_in[7];
    const float* W4  = (const float*)d_in[8];
    const float* b4  = (const float*)d_in[9];
    const float* W5  = (const float*)d_in[10];
    const float* b5  = (const float*)d_in[11];

    const int N = in_sizes[0] / 32;           // 1<<20
    float* outD = (float*)d_out;              // [N,16]
    float* outC = outD + (size_t)N * 16;      // [N,3]

    const int grid = N / ROWS_PER_BLOCK;      // 1024
    nerf_fused<<<grid, WAVES * 64, 0, stream>>>(pos, dir, W1, b1, W2, b2, W3, b3,
                                                W4, b4, W5, b5, outD, outC);
}

// Round 4
// 251.344 us; speedup vs baseline: 1.5795x; 1.0092x over previous
//
#include <hip/hip_runtime.h>
#include <hip/hip_bf16.h>

typedef __bf16 bf16_t;
typedef short  s4    __attribute__((ext_vector_type(4)));
typedef short  s8    __attribute__((ext_vector_type(8)));
typedef float  f32x4 __attribute__((ext_vector_type(4)));

#define TPW   16                     // 16-sample tiles per wave (processed in pairs)
#define WAVES 4
#define ROWS_PER_BLOCK (WAVES * TPW * 16)   // 1024 -> grid = 1024

__device__ __forceinline__ short bfs(float f) {
    return __builtin_bit_cast(short, (bf16_t)f);
}
__device__ __forceinline__ s4 pack4(f32x4 a) {
    s4 r; r[0]=bfs(a[0]); r[1]=bfs(a[1]); r[2]=bfs(a[2]); r[3]=bfs(a[3]); return r;
}
__device__ __forceinline__ s4 relu_pack4(f32x4 a) {
    s4 r;
    r[0]=bfs(fmaxf(a[0],0.f)); r[1]=bfs(fmaxf(a[1],0.f));
    r[2]=bfs(fmaxf(a[2],0.f)); r[3]=bfs(fmaxf(a[3],0.f));
    return r;
}
__device__ __forceinline__ s8 cat(s4 a, s4 b) {
    return __builtin_shufflevector(a, b, 0, 1, 2, 3, 4, 5, 6, 7);
}
// Native gfx950 shape: D = A*B + C, 16x16x32 bf16. k-map agnostic fragment
// construction (A and B gathered with the same per-(lane-group, elem) k order);
// C/D layout: col=lane&15, row=4*(lane>>4)+reg => a layer's D regs are exactly
// the next layer's B regs (after relu+pack+cat).
#define MFMA32(a,b,c) __builtin_amdgcn_mfma_f32_16x16x32_bf16(a, b, c, 0, 0, 0)

// NOTE: plain __launch_bounds__(256). A min-waves/EU of 4 (VGPR cap 128) forced
// ~70 regs of spills and a 2x regression (measured round 1). Two-tile ILP needs
// the 3-waves/SIMD tier (<=168 VGPR); wa3/wa4 live in LDS to stay under it.
__global__ __launch_bounds__(256) void nerf_fused(
    const float* __restrict__ pos, const float* __restrict__ dir,
    const float* __restrict__ W1, const float* __restrict__ b1,
    const float* __restrict__ W2, const float* __restrict__ b2,
    const float* __restrict__ W3, const float* __restrict__ b3,
    const float* __restrict__ W4, const float* __restrict__ b4,
    const float* __restrict__ W5, const float* __restrict__ b5,
    float* __restrict__ outD, float* __restrict__ outC)
{
    // wa3 (4 combos) and wa4 (8 combos) A-fragments, one copy per block.
    // Fragment depends on lane only; lane-contiguous 16B => conflict-free b128.
    __shared__ s8 w3lds[4 * 64];
    __shared__ s8 w4lds[8 * 64];

    const int tid  = threadIdx.x;
    const int w    = tid >> 6;
    const int lane = tid & 63;
    const int q    = lane >> 4;    // lane-group 0..3
    const int n    = lane & 15;    // A row / B col / sample-within-tile

    // ---------- VGPR-resident weight A-fragments (small layers) ----------
    s8 wa1[4], wa2x[2], wa5x[2];
    #pragma unroll
    for (int t = 0; t < 4; ++t)
        #pragma unroll
        for (int h = 0; h < 2; ++h)
            #pragma unroll
            for (int i = 0; i < 4; ++i)
                wa1[t][4*h+i] = bfs(W1[(16*h + 4*q + i) * 64 + 16*t + n]);      // [32,64]
    #pragma unroll
    for (int j = 0; j < 2; ++j)
        #pragma unroll
        for (int h = 0; h < 2; ++h)
            #pragma unroll
            for (int i = 0; i < 4; ++i)
                wa2x[j][4*h+i] = bfs(W2[(16*(2*j+h) + 4*q + i) * 16 + n]);      // [64,16]
    #pragma unroll
    for (int j = 0; j < 2; ++j)
        #pragma unroll
        for (int h = 0; h < 2; ++h)
            #pragma unroll
            for (int i = 0; i < 4; ++i)
                wa5x[j][4*h+i] = (n < 3) ? bfs(W5[(16*(2*j+h) + 4*q + i) * 3 + n])
                                         : (short)0;                             // [64,3] pad

    // ---------- LDS staging: wave w stages w3 combo w, w4 combos 2w,2w+1 ----------
    {
        s8 tmp;
        #pragma unroll
        for (int h = 0; h < 2; ++h)
            #pragma unroll
            for (int i = 0; i < 4; ++i)
                tmp[4*h+i] = bfs(W3[(16*h + 4*q + i) * 64 + 16*w + n]);         // [32,64]
        w3lds[w * 64 + lane] = tmp;
        #pragma unroll
        for (int cc = 0; cc < 2; ++cc) {
            s8 t4;
            #pragma unroll
            for (int h = 0; h < 2; ++h)
                #pragma unroll
                for (int i = 0; i < 4; ++i)
                    t4[4*h+i] = bfs(W4[(16*(2*cc+h) + 4*q + i) * 64 + 16*w + n]); // [64,64]
            w4lds[(2*w + cc) * 64 + lane] = t4;
        }
    }
    __syncthreads();   // LDS is read-only below: no further barriers/fences needed

    // ---------- bias C-initializers (channel index = 4q+r within tile t) ----------
    f32x4 bi1[4], bi3[4], bi4[4], bi2, bi5;
    #pragma unroll
    for (int t = 0; t < 4; ++t)
        #pragma unroll
        for (int r = 0; r < 4; ++r) {
            bi1[t][r] = b1[16*t + 4*q + r];
            bi3[t][r] = b3[16*t + 4*q + r];
            bi4[t][r] = b4[16*t + 4*q + r];
        }
    #pragma unroll
    for (int r = 0; r < 4; ++r) {
        bi2[r] = b2[4*q + r];
        bi5[r] = (q == 0 && r < 3) ? b5[r] : 0.f;
    }

    const int waveRow0 = blockIdx.x * ROWS_PER_BLOCK + w * (TPW * 16);

    // per-lane streaming pointers; tile B of each pair sits at fixed +offsets
    const float* pp = pos  + (size_t)(waveRow0 + n) * 32 + 4*q;
    const float* dp = dir  + (size_t)(waveRow0 + n) * 3;
    float*       pD = outD + (size_t)(waveRow0 + n) * 16 + 4*q;
    float*       pC = outC + (size_t)(waveRow0 + n) * 3;   // only used by q==0 lanes

    // prefetched raw inputs for pair 0 (tiles 0 and 1)
    f32x4 paA = *(const f32x4*)pp;
    f32x4 pbA = *(const f32x4*)(pp + 16);
    f32x4 paB = *(const f32x4*)(pp + 512);
    f32x4 pbB = *(const f32x4*)(pp + 528);
    float dxA = dp[0], dyA = dp[1], dzA = dp[2];
    float dxB = dp[48], dyB = dp[49], dzB = dp[50];

    for (int t = 0; t < TPW; t += 2) {
        // prefetch next pair's inputs (hide HBM latency under this pair's MFMAs)
        const float* ppn = pp + ((t + 2 < TPW) ? 2 * 16 * 32 : 0);
        const float* dpn = dp + ((t + 2 < TPW) ? 2 * 16 * 3  : 0);
        f32x4 paA2 = *(const f32x4*)ppn;
        f32x4 pbA2 = *(const f32x4*)(ppn + 16);
        f32x4 paB2 = *(const f32x4*)(ppn + 512);
        f32x4 pbB2 = *(const f32x4*)(ppn + 528);
        float dxA2 = dpn[0],  dyA2 = dpn[1],  dzA2 = dpn[2];
        float dxB2 = dpn[48], dyB2 = dpn[49], dzB2 = dpn[50];

        s8 xbA = cat(pack4(paA), pack4(pbA));
        s8 xbB = cat(pack4(paB), pack4(pbB));

        // ---- L1: two independent chains, shared weights ----
        s4 hfA[4], hfB[4];
        #pragma unroll
        for (int tt = 0; tt < 4; ++tt) {
            f32x4 hA = MFMA32(wa1[tt], xbA, bi1[tt]);
            f32x4 hB = MFMA32(wa1[tt], xbB, bi1[tt]);
            hfA[tt] = relu_pack4(hA);
            hfB[tt] = relu_pack4(hB);
        }

        // ---- L2: density (K=64 -> 2 chained MFMAs each, A/B interleaved) ----
        f32x4 d2A = MFMA32(wa2x[0], cat(hfA[0], hfA[1]), bi2);
        f32x4 d2B = MFMA32(wa2x[0], cat(hfB[0], hfB[1]), bi2);
        d2A = MFMA32(wa2x[1], cat(hfA[2], hfA[3]), d2A);
        d2B = MFMA32(wa2x[1], cat(hfB[2], hfB[3]), d2B);

        // direct coalesced density stores (lane(q,n): channels 4q..4q+3 of sample n)
        *(f32x4*)pD         = d2A;
        *(f32x4*)(pD + 256) = d2B;

        // ---- SH encodings for both tiles ----
        f32x4 shvA, shvB;
        {
            const float xx = dxA*dxA, yy = dyA*dyA, zz = dzA*dzA;
            if (q == 0) {
                shvA[0] = 0.28209479177387814f;
                shvA[1] = 0.4886025119029199f * dyA;
                shvA[2] = 0.4886025119029199f * dzA;
                shvA[3] = 0.4886025119029199f * dxA;
            } else if (q == 1) {
                shvA[0] = 1.0925484305920792f * dxA * dyA;
                shvA[1] = 1.0925484305920792f * dyA * dzA;
                shvA[2] = 0.9461746957575601f * zz - 0.31539156525252f;
                shvA[3] = 1.0925484305920792f * dxA * dzA;
            } else if (q == 2) {
                shvA[0] = 0.5462742152960396f * (xx - yy);
                shvA[1] = 0.5900435899266435f * dyA * (3.f*xx - yy);
                shvA[2] = 2.890611442640554f * dxA * dyA * dzA;
                shvA[3] = 0.4570457994644658f * dyA * (5.f*zz - 1.f);
            } else {
                shvA[0] = 0.3731763325901154f * dzA * (5.f*zz - 3.f);
                shvA[1] = 0.4570457994644658f * dxA * (5.f*zz - 1.f);
                shvA[2] = 1.445305721320277f  * dzA * (xx - yy);
                shvA[3] = 0.5900435899266435f * dxA * (xx - 3.f*yy);
            }
        }
        {
            const float xx = dxB*dxB, yy = dyB*dyB, zz = dzB*dzB;
            if (q == 0) {
                shvB[0] = 0.28209479177387814f;
                shvB[1] = 0.4886025119029199f * dyB;
                shvB[2] = 0.4886025119029199f * dzB;
                shvB[3] = 0.4886025119029199f * dxB;
            } else if (q == 1) {
                shvB[0] = 1.0925484305920792f * dxB * dyB;
                shvB[1] = 1.0925484305920792f * dyB * dzB;
                shvB[2] = 0.9461746957575601f * zz - 0.31539156525252f;
                shvB[3] = 1.0925484305920792f * dxB * dzB;
            } else if (q == 2) {
                shvB[0] = 0.5462742152960396f * (xx - yy);
                shvB[1] = 0.5900435899266435f * dyB * (3.f*xx - yy);
                shvB[2] = 2.890611442640554f * dxB * dyB * dzB;
                shvB[3] = 0.4570457994644658f * dyB * (5.f*zz - 1.f);
            } else {
                shvB[0] = 0.3731763325901154f * dzB * (5.f*zz - 3.f);
                shvB[1] = 0.4570457994644658f * dxB * (5.f*zz - 1.f);
                shvB[2] = 1.445305721320277f  * dzB * (xx - yy);
                shvB[3] = 0.5900435899266435f * dxB * (xx - 3.f*yy);
            }
        }
        s8 cfA = cat(pack4(d2A), pack4(shvA));
        s8 cfB = cat(pack4(d2B), pack4(shvB));

        // ---- L3: weights from LDS (conflict-free b128), shared by A/B ----
        s4 gfA[4], gfB[4];
        #pragma unroll
        for (int tt = 0; tt < 4; ++tt) {
            s8 wf = w3lds[tt * 64 + lane];
            f32x4 gA = MFMA32(wf, cfA, bi3[tt]);
            f32x4 gB = MFMA32(wf, cfB, bi3[tt]);
            gfA[tt] = relu_pack4(gA);
            gfB[tt] = relu_pack4(gB);
        }

        // ---- L4: weights from LDS, K=64 -> 2 chained MFMAs per tile per tt ----
        s8 glA = cat(gfA[0], gfA[1]), ghA = cat(gfA[2], gfA[3]);
        s8 glB = cat(gfB[0], gfB[1]), ghB = cat(gfB[2], gfB[3]);
        s4 efA[4], efB[4];
        #pragma unroll
        for (int tt = 0; tt < 4; ++tt) {
            s8 w0 = w4lds[(tt*2 + 0) * 64 + lane];
            s8 w1 = w4lds[(tt*2 + 1) * 64 + lane];
            f32x4 eA = MFMA32(w0, glA, bi4[tt]);
            f32x4 eB = MFMA32(w0, glB, bi4[tt]);
            eA = MFMA32(w1, ghA, eA);
            eB = MFMA32(w1, ghB, eB);
            efA[tt] = relu_pack4(eA);
            efB[tt] = relu_pack4(eB);
        }

        // ---- L5: color + sigmoid (valid only q==0, r<3) ----
        f32x4 c5A = MFMA32(wa5x[0], cat(efA[0], efA[1]), bi5);
        f32x4 c5B = MFMA32(wa5x[0], cat(efB[0], efB[1]), bi5);
        c5A = MFMA32(wa5x[1], cat(efA[2], efA[3]), c5A);
        c5B = MFMA32(wa5x[1], cat(efB[2], efB[3]), c5B);

        f32x4 cvA, cvB;
        cvA[0] = 1.f / (1.f + __expf(-c5A[0]));
        cvA[1] = 1.f / (1.f + __expf(-c5A[1]));
        cvA[2] = 1.f / (1.f + __expf(-c5A[2]));
        cvB[0] = 1.f / (1.f + __expf(-c5B[0]));
        cvB[1] = 1.f / (1.f + __expf(-c5B[1]));
        cvB[2] = 1.f / (1.f + __expf(-c5B[2]));
        if (q == 0) {
            pC[0] = cvA[0]; pC[1] = cvA[1]; pC[2] = cvA[2];
            pC[48] = cvB[0]; pC[49] = cvB[1]; pC[50] = cvB[2];
        }

        pp += 2 * 16 * 32; dp += 2 * 16 * 3; pD += 2 * 16 * 16; pC += 2 * 16 * 3;
        paA = paA2; pbA = pbA2; paB = paB2; pbB = pbB2;
        dxA = dxA2; dyA = dyA2; dzA = dzA2;
        dxB = dxB2; dyB = dyB2; dzB = dzB2;
    }
}

extern "C" void kernel_launch(void* const* d_in, const int* in_sizes, int n_in,
                              void* d_out, int out_size, void* d_ws, size_t ws_size,
                              hipStream_t stream) {
    const float* pos = (const float*)d_in[0];
    const float* dir = (const float*)d_in[1];
    const float* W1  = (const float*)d_in[2];
    const float* b1  = (const float*)d_in[3];
    const float* W2  = (const float*)d_in[4];
    const float* b2  = (const float*)d_in[5];
    const float* W3  = (const float*)d_in[6];
    const float* b3  = (const float*)d_in[7];
    const float* W4  = (const float*)d_in[8];
    const float* b4  = (const float*)d_in[9];
    const float* W5  = (const float*)d_in[10];
    const float* b5  = (const float*)d_in[11];

    const int N = in_sizes[0] / 32;           // 1<<20
    float* outD = (float*)d_out;              // [N,16]
    float* outC = outD + (size_t)N * 16;      // [N,3]

    const int grid = N / ROWS_PER_BLOCK;      // 1024
    nerf_fused<<<grid, WAVES * 64, 0, stream>>>(pos, dir, W1, b1, W2, b2, W3, b3,
                                                W4, b4, W5, b5, outD, outC);
}